// Round 8
// baseline (1663.247 us; speedup 1.0000x reference)
//
#include <hip/hip_runtime.h>
#include <hip/hip_bf16.h>

typedef __hip_bfloat16 hb;
typedef __bf16 bf16x8 __attribute__((ext_vector_type(8)));
typedef float f32x4 __attribute__((ext_vector_type(4)));

#define N_DEPTH 6
#define N_DIM   512
#define N_HEADS 8
#define N_MLP   2048
#define N_TOK   197
#define N_PATCH 196
#define N_BATCH 64
#define ROWS    (N_BATCH * N_TOK)     /* 12608 */
#define ROWS_PAD 12672                /* 99 * 128 */
#define PROWS   (N_BATCH * N_PATCH)   /* 12544 = 98 * 128 */

// ---------------- workspace layout (bytes) ----------------
#define OFF_WPATCH 0u
#define OFF_WQKV   786432u
#define OFF_WOUT   10223616u
#define OFF_WFC1   13369344u
#define OFF_WFC2   25952256u
#define OFF_XBF    38535168u          /* x_bf swizzled A-layout (K=512) */
#define OFF_CTX    51511296u          /* ctx  swizzled A-layout (K=512) */
#define OFF_BIG    64487424u          /* Xp / qkv(row-major) / hmid swizzled (51.9 MB) */
#define OFF_XF     116391936u
#define OFF_H1     142344192u
/* total 168,296,448 B */

// Swizzled A/B fragment layout for 16x16x32 MFMA (KB = K/32):
// elem(row r, col k) -> (((mb*KB + kb)*2 + wr)*4 + t)*512 + quad*128 + r16*8 + e
__device__ __forceinline__ size_t swoff(int row, int k, int KB) {
    return (size_t)((((row >> 7) * KB + (k >> 5)) * 2 + ((row >> 6) & 1)) * 4 + ((row >> 4) & 3)) * 512
           + ((k >> 3) & 3) * 128 + (row & 15) * 8 + (k & 7);
}

// async global->LDS, 16B per lane (patch-embed GEMM only)
__device__ __forceinline__ void gl2lds(const hb* g, hb* l) {
    __builtin_amdgcn_global_load_lds((const __attribute__((address_space(1))) unsigned int*)g,
                                     (__attribute__((address_space(3))) unsigned int*)l, 16, 0, 0);
}

// ---------------- weight swizzle (fp32 row-major -> bf16 fragment order) ----------------

__global__ void wsw_kernel(const float* __restrict__ W, hb* __restrict__ out, int K, int N) {
    const int layer = blockIdx.y;
    const float* Wl = W + (size_t)layer * N * K;
    hb* ol = out + (size_t)layer * N * K;
    int idx = blockIdx.x * 256 + threadIdx.x;
    if (idx >= N * (K >> 3)) return;
    int n = idx / (K >> 3), kc = idx % (K >> 3);
    int k = kc * 8;
    hb tmp[8] __attribute__((aligned(16)));
#pragma unroll
    for (int j = 0; j < 8; ++j) tmp[j] = __float2bfloat16(Wl[(size_t)n * K + k + j]);
    *(float4*)(ol + swoff(n, k, K >> 5)) = *(const float4*)tmp;
}

__global__ void cvt_bf16_kernel(const float* __restrict__ in, hb* __restrict__ out, int n) {
    int t = blockIdx.x * 256 + threadIdx.x;
    if (t < n) out[t] = __float2bfloat16(in[t]);
}

// ---------------- small utility kernels ----------------

__global__ void patchify_kernel(const float* __restrict__ img, hb* __restrict__ Xp) {
    int t = blockIdx.x * 256 + threadIdx.x;
    if (t >= PROWS * 768) return;
    int r = t / 768, j = t % 768;
    int b = r / 196, p = r % 196;
    int ph = p / 14, pw = p % 14;
    int p1 = j / 48, jr = j % 48;
    int p2 = jr / 3, c = jr % 3;
    float v = img[(((size_t)b * 3 + c) * 224 + ph * 16 + p1) * 224 + pw * 16 + p2];
    Xp[t] = __float2bfloat16(v);
}

__global__ void cls_init_kernel(const float* __restrict__ cls, const float* __restrict__ pos,
                                float* __restrict__ xf, hb* __restrict__ xb) {
    int t = blockIdx.x * 256 + threadIdx.x;   // 64*512
    int b = t >> 9, c = t & 511;
    float v = cls[c] + pos[c];
    int row = b * N_TOK;
    xf[(size_t)row * N_DIM + c] = v;
    xb[swoff(row, c, 16)] = __float2bfloat16(v);
}

__global__ void zero_pads_kernel(float* __restrict__ xf, hb* __restrict__ xb, hb* __restrict__ ctx) {
    int t = blockIdx.x * 256 + threadIdx.x;   // 64*512 elements
    xf[(size_t)ROWS * N_DIM + t] = 0.f;
    int kb = t >> 11, r2 = t & 2047;
    size_t off = (size_t)((98 * 16 + kb) * 2 + 1) * 2048 + r2;
    hb z = __float2bfloat16(0.f);
    xb[off] = z;
    ctx[off] = z;
}

__global__ void extract_cls_kernel(const float* __restrict__ xf, float* __restrict__ out) {
    int t = blockIdx.x * 256 + threadIdx.x;   // 64*512
    int b = t >> 9, c = t & 511;
    out[t] = xf[((size_t)b * N_TOK) * N_DIM + c];
}

// ---------------- LayerNorm (fp32 in -> fp32 row + bf16 swizzled), 1 wave per row ----------------

__global__ void __launch_bounds__(256) ln_kernel(const float* __restrict__ in,
                                                 const float* __restrict__ w, const float* __restrict__ b,
                                                 float* __restrict__ outf, hb* __restrict__ outb, int rows) {
    int row = blockIdx.x * 4 + (threadIdx.x >> 6);
    int lane = threadIdx.x & 63;
    if (row >= rows) return;
    const float* p = in + (size_t)row * N_DIM;
    float4 v0 = *(const float4*)(p + lane * 8);
    float4 v1 = *(const float4*)(p + lane * 8 + 4);
    float xs[8] = {v0.x, v0.y, v0.z, v0.w, v1.x, v1.y, v1.z, v1.w};
    float s = 0.f, q = 0.f;
#pragma unroll
    for (int j = 0; j < 8; ++j) { s += xs[j]; q += xs[j] * xs[j]; }
#pragma unroll
    for (int o = 32; o > 0; o >>= 1) { s += __shfl_xor(s, o); q += __shfl_xor(q, o); }
    float mean = s * (1.f / 512.f);
    float var = q * (1.f / 512.f) - mean * mean;
    float r = rsqrtf(var + 1e-5f);
    float4 w0 = *(const float4*)(w + lane * 8);
    float4 w1 = *(const float4*)(w + lane * 8 + 4);
    float4 b0 = *(const float4*)(b + lane * 8);
    float4 b1 = *(const float4*)(b + lane * 8 + 4);
    float ws8[8] = {w0.x, w0.y, w0.z, w0.w, w1.x, w1.y, w1.z, w1.w};
    float bs8[8] = {b0.x, b0.y, b0.z, b0.w, b1.x, b1.y, b1.z, b1.w};
    float of[8] __attribute__((aligned(16)));
    hb tb[8] __attribute__((aligned(16)));
#pragma unroll
    for (int j = 0; j < 8; ++j) {
        float y = (xs[j] - mean) * r * ws8[j] + bs8[j];
        of[j] = y;
        tb[j] = __float2bfloat16(y);
    }
    *(float4*)(outf + (size_t)row * N_DIM + lane * 8)     = *(const float4*)&of[0];
    *(float4*)(outf + (size_t)row * N_DIM + lane * 8 + 4) = *(const float4*)&of[4];
    *(float4*)(outb + swoff(row, lane * 8, 16)) = *(const float4*)tb;
}

// ---------------- barrier-free swizzled GEMM, depth-4 rotating prefetch ----------------
// A, B in fragment-swizzled layout. K-loop: 8 coalesced dwordx4 loads + 16 MFMA,
// rotating 4-deep operand buffers (kb%4 static via full divisibility), NO LDS, NO barriers.
// MODE 0: out_bf row-major = acc + bias            (qkv)
// MODE 1: out_bf SWIZZLED = gelu_tanh(acc + bias)  (fc1 -> hmid)
// MODE 2: out_f32 row-major = acc + bias + res     (out_proj, fc2)

template <int K, int MODE>
__global__ void __launch_bounds__(256) gemm_sw(const hb* __restrict__ A, const hb* __restrict__ B,
                                               const float* __restrict__ bias, int N,
                                               hb* __restrict__ outb, float* __restrict__ outf,
                                               const float* __restrict__ res) {
    constexpr int KB = K / 32;
    constexpr int PF = 4;            // prefetch depth; KB % PF == 0 for K=512/2048
    static_assert(KB % PF == 0, "KB must be divisible by PF");
    __shared__ hb Sm[4][2560];       // per-wave epilogue bounce, stride 40 (MODE 0/1)
    const int tid = threadIdx.x;
    const int lane = tid & 63, wid = tid >> 6;
    const int wr = wid >> 1, wc = wid & 1;
    const int quad = lane >> 4, r16 = lane & 15;
    const int mb = blockIdx.y, nb = blockIdx.x;
    const int m0 = mb * 128, n0 = nb * 128;

    const hb* pa = A + (size_t)mb * KB * 4096 + wr * 2048 + lane * 8;
    const hb* pb = B + (size_t)nb * KB * 4096 + wc * 2048 + lane * 8;

    f32x4 acc[4][4] = {};
    bf16x8 abuf[PF][4], bbuf[PF][4];
#pragma unroll
    for (int p = 0; p < PF; ++p) {
        size_t o = (size_t)p * 4096;
#pragma unroll
        for (int t = 0; t < 4; ++t) {
            abuf[p][t] = *(const bf16x8*)(pa + o + t * 512);
            bbuf[p][t] = *(const bf16x8*)(pb + o + t * 512);
        }
    }
#pragma unroll 4
    for (int kb = 0; kb < KB; ++kb) {
        const int cur = kb % PF;     // static after unroll-4 (KB % 4 == 0)
#pragma unroll
        for (int mi = 0; mi < 4; ++mi)
#pragma unroll
            for (int nj = 0; nj < 4; ++nj)
                acc[mi][nj] = __builtin_amdgcn_mfma_f32_16x16x32_bf16(abuf[cur][mi], bbuf[cur][nj], acc[mi][nj], 0, 0, 0);
        if (kb + PF < KB) {
            size_t o = (size_t)(kb + PF) * 4096;
#pragma unroll
            for (int t = 0; t < 4; ++t) {
                abuf[cur][t] = *(const bf16x8*)(pa + o + t * 512);
                bbuf[cur][t] = *(const bf16x8*)(pb + o + t * 512);
            }
        }
    }

    if constexpr (MODE == 0 || MODE == 1) {
        hb* Cb = &Sm[wid][0];
#pragma unroll
        for (int p = 0; p < 2; ++p) {
#pragma unroll
            for (int nj2 = 0; nj2 < 2; ++nj2) {
                int nj = p * 2 + nj2;
                float bv = bias[n0 + wc * 64 + nj * 16 + r16];
#pragma unroll
                for (int mi = 0; mi < 4; ++mi)
#pragma unroll
                    for (int e = 0; e < 4; ++e) {
                        float v = acc[mi][nj][e] + bv;
                        if constexpr (MODE == 1) {
                            float y = 0.79788456f * (v + 0.044715f * v * v * v);
                            float t = 1.f - 2.f / (__expf(2.f * y) + 1.f);
                            v = 0.5f * v * (1.f + t);
                        }
                        Cb[(mi * 16 + quad * 4 + e) * 40 + nj2 * 16 + r16] = __float2bfloat16(v);
                    }
            }
            if constexpr (MODE == 0) {
#pragma unroll
                for (int it = 0; it < 4; ++it) {
                    int idx = it * 64 + lane;
                    int row = idx >> 2, ch = idx & 3;
                    bf16x8 val = *(const bf16x8*)&Cb[row * 40 + ch * 8];
                    *(bf16x8*)(outb + (size_t)(m0 + wr * 64 + row) * N + n0 + wc * 64 + p * 32 + ch * 8) = val;
                }
            } else {
                size_t base = ((((size_t)mb * (N >> 5) + ((n0 + wc * 64 + p * 32) >> 5)) * 2 + wr) * 4) * 512;
#pragma unroll
                for (int it = 0; it < 4; ++it) {
                    bf16x8 val = *(const bf16x8*)&Cb[(it * 16 + r16) * 40 + quad * 8];
                    *(bf16x8*)(outb + base + it * 512 + lane * 8) = val;
                }
            }
        }
    } else {  // MODE 2
#pragma unroll
        for (int nj = 0; nj < 4; ++nj) {
            int col = n0 + wc * 64 + nj * 16 + r16;
            float bv = bias[col];
#pragma unroll
            for (int mi = 0; mi < 4; ++mi)
#pragma unroll
                for (int e = 0; e < 4; ++e) {
                    int row = m0 + wr * 64 + mi * 16 + quad * 4 + e;
                    outf[(size_t)row * N + col] = acc[mi][nj][e] + bv + res[(size_t)row * N + col];
                }
        }
    }
}

// ---------------- patch-embed GEMM (LDS-staged, XOR swizzle; runs once) ----------------

__global__ void __launch_bounds__(256) gemm_pe(const hb* __restrict__ A, const hb* __restrict__ B,
                                               const float* __restrict__ bias, int K, int N,
                                               hb* __restrict__ outb, float* __restrict__ outf,
                                               const float* __restrict__ pos) {
    __shared__ hb Sm[8192];
    hb* As = Sm;
    hb* Bs = Sm + 4096;
    const int tid = threadIdx.x;
    const int lane = tid & 63, wid = tid >> 6;
    const int wr = wid >> 1, wc = wid & 1;
    const int quad = lane >> 4, r16 = lane & 15;
    const int m0 = blockIdx.y * 128, n0 = blockIdx.x * 128;

    const int r0 = lane >> 2;
    const int c0 = (lane & 3) ^ ((lane >> 3) & 3);
    const hb* ga0 = A + (size_t)(m0 + wid * 32 + r0) * K + c0 * 8;
    const hb* ga1 = ga0 + (size_t)16 * K;
    const hb* gb0 = B + (size_t)(n0 + wid * 32 + r0) * K + c0 * 8;
    const hb* gb1 = gb0 + (size_t)16 * K;
    hb* la0 = As + (wid * 32) * 32;
    hb* la1 = la0 + 16 * 32;
    hb* lb0 = Bs + (wid * 32) * 32;
    hb* lb1 = lb0 + 16 * 32;
    const int sw = (r16 >> 1) & 3;
    const int pa = (quad ^ sw) * 8;

    f32x4 acc[4][4] = {};
    for (int k0 = 0; k0 < K; k0 += 32) {
        gl2lds(ga0, la0);
        gl2lds(ga1, la1);
        gl2lds(gb0, lb0);
        gl2lds(gb1, lb1);
        ga0 += 32; ga1 += 32; gb0 += 32; gb1 += 32;
        __syncthreads();
        bf16x8 af[4], bfr[4];
#pragma unroll
        for (int t = 0; t < 4; ++t) {
            af[t]  = *(const bf16x8*)&As[(wr * 64 + t * 16 + r16) * 32 + pa];
            bfr[t] = *(const bf16x8*)&Bs[(wc * 64 + t * 16 + r16) * 32 + pa];
        }
#pragma unroll
        for (int mi = 0; mi < 4; ++mi)
#pragma unroll
            for (int nj = 0; nj < 4; ++nj)
                acc[mi][nj] = __builtin_amdgcn_mfma_f32_16x16x32_bf16(af[mi], bfr[nj], acc[mi][nj], 0, 0, 0);
        __syncthreads();
    }

#pragma unroll
    for (int nj = 0; nj < 4; ++nj) {
        int col = n0 + wc * 64 + nj * 16 + r16;
        float bv = bias[col];
#pragma unroll
        for (int mi = 0; mi < 4; ++mi)
#pragma unroll
            for (int e = 0; e < 4; ++e) {
                int row = m0 + wr * 64 + mi * 16 + quad * 4 + e;
                float v = acc[mi][nj][e] + bv;
                int pidx = row % 196;
                int row2 = row + row / 196 + 1;
                v += pos[(size_t)(pidx + 1) * N_DIM + col];
                outf[(size_t)row2 * N_DIM + col] = v;
                outb[swoff(row2, col, 16)] = __float2bfloat16(v);
            }
    }
}

// ---------------- MFMA flash attention: one block per (b, h) ----------------

__global__ void __launch_bounds__(256, 2) attn_kernel(const hb* __restrict__ qkv,
                                                      hb* __restrict__ ctx) {
    __shared__ hb Ks[224 * 64];
    __shared__ hb Vs[224 * 64];
    __shared__ hb Pb[4][16 * 40];
    const int bh = blockIdx.x;
    const int b = bh >> 3, h = bh & 7;
    const int tid = threadIdx.x, lane = tid & 63, wid = tid >> 6;
    const int quad = lane >> 4, r16 = lane & 15;
    const hb* base = qkv + (size_t)(b * N_TOK) * 1536 + h * 64;

#pragma unroll
    for (int i = 0; i < 7; ++i) {
        int idx = tid + i * 256;
        int m = idx >> 3, c = idx & 7;
        bf16x8 kv = {}, vv = {};
        if (m < 197) {
            kv = *(const bf16x8*)(base + (size_t)m * 1536 + 512 + c * 8);
            vv = *(const bf16x8*)(base + (size_t)m * 1536 + 1024 + c * 8);
        }
        *(bf16x8*)&Ks[m * 64 + c * 8] = kv;
        *(bf16x8*)&Vs[m * 64 + c * 8] = vv;
    }

    bf16x8 af[4][2];
#pragma unroll
    for (int mi = 0; mi < 4; ++mi) {
        int q = wid * 64 + mi * 16 + r16;
#pragma unroll
        for (int kc = 0; kc < 2; ++kc)
            af[mi][kc] = *(const bf16x8*)(base + (size_t)q * 1536 + kc * 32 + quad * 8);
    }

    f32x4 o[4][4] = {};
    float mst[4][4], lp[4][4];
#pragma unroll
    for (int mi = 0; mi < 4; ++mi)
#pragma unroll
        for (int e = 0; e < 4; ++e) { mst[mi][e] = -3.0e38f; lp[mi][e] = 0.f; }

    __syncthreads();

    const __bf16* VsB = (const __bf16*)Vs;
    for (int kt = 0; kt < 7; ++kt) {
        bf16x8 bk[2][2], bv[4];
#pragma unroll
        for (int nj = 0; nj < 2; ++nj)
#pragma unroll
            for (int kc = 0; kc < 2; ++kc)
                bk[nj][kc] = *(const bf16x8*)&Ks[(kt * 32 + nj * 16 + r16) * 64 + kc * 32 + quad * 8];
#pragma unroll
        for (int jd = 0; jd < 4; ++jd) {
            bf16x8 t;
#pragma unroll
            for (int j = 0; j < 8; ++j)
                t[j] = VsB[(kt * 32 + quad * 8 + j) * 64 + jd * 16 + r16];
            bv[jd] = t;
        }

        const bool v0 = (kt * 32 + r16) < N_TOK;
        const bool v1 = (kt * 32 + 16 + r16) < N_TOK;

#pragma unroll
        for (int mi = 0; mi < 4; ++mi) {
            f32x4 z = {};
            f32x4 s0v = __builtin_amdgcn_mfma_f32_16x16x32_bf16(af[mi][0], bk[0][0], z, 0, 0, 0);
            s0v = __builtin_amdgcn_mfma_f32_16x16x32_bf16(af[mi][1], bk[0][1], s0v, 0, 0, 0);
            f32x4 s1v = __builtin_amdgcn_mfma_f32_16x16x32_bf16(af[mi][0], bk[1][0], z, 0, 0, 0);
            s1v = __builtin_amdgcn_mfma_f32_16x16x32_bf16(af[mi][1], bk[1][1], s1v, 0, 0, 0);

            float al[4];
#pragma unroll
            for (int e = 0; e < 4; ++e) {
                float s0 = v0 ? s0v[e] * 0.125f : -1e30f;
                float s1 = v1 ? s1v[e] * 0.125f : -1e30f;
                float mx = fmaxf(s0, s1);
#pragma unroll
                for (int off = 1; off < 16; off <<= 1) mx = fmaxf(mx, __shfl_xor(mx, off));
                float mnew = fmaxf(mst[mi][e], mx);
                float alpha = __expf(mst[mi][e] - mnew);
                mst[mi][e] = mnew;
                float p0 = __expf(s0 - mnew);
                float p1 = __expf(s1 - mnew);
                lp[mi][e] = lp[mi][e] * alpha + p0 + p1;
                al[e] = alpha;
                int prow = (quad * 4 + e) * 40;
                Pb[wid][prow + r16]      = __float2bfloat16(p0);
                Pb[wid][prow + 16 + r16] = __float2bfloat16(p1);
            }
#pragma unroll
            for (int jd = 0; jd < 4; ++jd)
#pragma unroll
                for (int e = 0; e < 4; ++e) o[mi][jd][e] *= al[e];
            bf16x8 ap = *(const bf16x8*)&Pb[wid][r16 * 40 + quad * 8];
#pragma unroll
            for (int jd = 0; jd < 4; ++jd)
                o[mi][jd] = __builtin_amdgcn_mfma_f32_16x16x32_bf16(ap, bv[jd], o[mi][jd], 0, 0, 0);
        }
    }

#pragma unroll
    for (int mi = 0; mi < 4; ++mi) {
        float rl[4];
#pragma unroll
        for (int e = 0; e < 4; ++e) {
            float l = lp[mi][e];
#pragma unroll
            for (int off = 1; off < 16; off <<= 1) l += __shfl_xor(l, off);
            rl[e] = 1.f / l;
        }
        int qrow = wid * 64 + mi * 16 + quad * 4;
#pragma unroll
        for (int e = 0; e < 4; ++e) {
            int q = qrow + e;
            if (q < N_TOK) {
                int row = b * N_TOK + q;
#pragma unroll
                for (int jd = 0; jd < 4; ++jd)
                    ctx[swoff(row, h * 64 + jd * 16 + r16, 16)] = __float2bfloat16(o[mi][jd][e] * rl[e]);
            }
        }
    }
}

// ---------------- launch ----------------

extern "C" void kernel_launch(void* const* d_in, const int* in_sizes, int n_in,
                              void* d_out, int out_size, void* d_ws, size_t ws_size,
                              hipStream_t stream) {
    (void)in_sizes; (void)n_in; (void)out_size; (void)ws_size;
    const float* img     = (const float*)d_in[0];
    const float* patch_w = (const float*)d_in[1];
    const float* patch_b = (const float*)d_in[2];
    const float* cls_t   = (const float*)d_in[3];
    const float* pos     = (const float*)d_in[4];
    const float* w_qkv   = (const float*)d_in[5];
    const float* b_qkv   = (const float*)d_in[6];
    const float* w_out   = (const float*)d_in[7];
    const float* b_out   = (const float*)d_in[8];
    const float* ln1w    = (const float*)d_in[9];
    const float* ln1b    = (const float*)d_in[10];
    const float* w_fc1   = (const float*)d_in[11];
    const float* b_fc1   = (const float*)d_in[12];
    const float* w_fc2   = (const float*)d_in[13];
    const float* b_fc2   = (const float*)d_in[14];
    const float* ln2w    = (const float*)d_in[15];
    const float* ln2b    = (const float*)d_in[16];

    char* ws = (char*)d_ws;
    hb* wPatch = (hb*)(ws + OFF_WPATCH);
    hb* wQKV   = (hb*)(ws + OFF_WQKV);
    hb* wOut   = (hb*)(ws + OFF_WOUT);
    hb* wFc1   = (hb*)(ws + OFF_WFC1);
    hb* wFc2   = (hb*)(ws + OFF_WFC2);
    hb* x_bf   = (hb*)(ws + OFF_XBF);
    hb* ctx    = (hb*)(ws + OFF_CTX);
    hb* Xp     = (hb*)(ws + OFF_BIG);
    hb* qkv    = (hb*)(ws + OFF_BIG);
    hb* hmid   = (hb*)(ws + OFF_BIG);
    float* x_f = (float*)(ws + OFF_XF);
    float* h1  = (float*)(ws + OFF_H1);

    cvt_bf16_kernel<<<dim3((512 * 768 + 255) / 256), dim3(256), 0, stream>>>(patch_w, wPatch, 512 * 768);
    wsw_kernel<<<dim3(384, 6), dim3(256), 0, stream>>>(w_qkv, wQKV, 512, 1536);
    wsw_kernel<<<dim3(128, 6), dim3(256), 0, stream>>>(w_out, wOut, 512, 512);
    wsw_kernel<<<dim3(512, 6), dim3(256), 0, stream>>>(w_fc1, wFc1, 512, 2048);
    wsw_kernel<<<dim3(512, 6), dim3(256), 0, stream>>>(w_fc2, wFc2, 2048, 512);

    patchify_kernel<<<dim3((PROWS * 768 + 255) / 256), dim3(256), 0, stream>>>(img, Xp);
    gemm_pe<<<dim3(4, 98), dim3(256), 0, stream>>>(Xp, wPatch, patch_b, 768, 512, x_bf, x_f, pos);
    cls_init_kernel<<<dim3(128), dim3(256), 0, stream>>>(cls_t, pos, x_f, x_bf);
    zero_pads_kernel<<<dim3(128), dim3(256), 0, stream>>>(x_f, x_bf, ctx);

    for (int i = 0; i < N_DEPTH; ++i) {
        gemm_sw<512, 0><<<dim3(12, 99), dim3(256), 0, stream>>>(x_bf, wQKV + (size_t)i * 1536 * 512,
                                                                b_qkv + i * 1536, 1536, qkv, nullptr, nullptr);
        attn_kernel<<<dim3(512), dim3(256), 0, stream>>>(qkv, ctx);
        gemm_sw<512, 2><<<dim3(4, 99), dim3(256), 0, stream>>>(ctx, wOut + (size_t)i * 512 * 512,
                                                               b_out + i * 512, 512, nullptr, h1, x_f);
        ln_kernel<<<dim3(3152), dim3(256), 0, stream>>>(h1, ln1w + i * 512, ln1b + i * 512, x_f, x_bf, ROWS);
        gemm_sw<512, 1><<<dim3(16, 99), dim3(256), 0, stream>>>(x_bf, wFc1 + (size_t)i * 2048 * 512,
                                                                b_fc1 + i * 2048, 2048, hmid, nullptr, nullptr);
        gemm_sw<2048, 2><<<dim3(4, 99), dim3(256), 0, stream>>>(hmid, wFc2 + (size_t)i * 512 * 2048,
                                                                b_fc2 + i * 512, 512, nullptr, h1, x_f);
        ln_kernel<<<dim3(3152), dim3(256), 0, stream>>>(h1, ln2w + i * 512, ln2b + i * 512, x_f, x_bf, ROWS);
    }

    extract_cls_kernel<<<dim3(128), dim3(256), 0, stream>>>(x_f, (float*)d_out);
}